// Round 6
// baseline (237.253 us; speedup 1.0000x reference)
//
#include <hip/hip_runtime.h>

// AR(24) rollout: out[b,t,d], t in [0,168), from last 24 timesteps of x[b,:,d].
//
// Graph anatomy: dur_us includes ~216.4 us of harness 0xAA fills (2 x 672 MiB
// at 6.5 TB/s -- the measured achievable ceiling on this chip). Kernel floor
// = 100.7 MB / 6.5 TB/s = 15.5 us; full-graph roofline ~232 us.
//
// Empirical ladder (kernel-only us): scalar 23.4 | float2 NT 19.8 | float4 NT
// 27.0 | plain vs NT stores: null (R7). Model: kernel ~= per-wave-FMA-issue
// + ~13.2 us write drain, ADDITIVE at 1 wave/SIMD (issue and drain don't
// overlap; occupancy can't rise without redundant compute -- refuted R3).
// R8: halve the issue term. gfx950 has v_pk_fma_f32 (VOP3P, 2 full-precision
// FP32 FMAs/inst, per-element rounding == v_fma_f32). Express the two chains
// of the float2 pair as a vector FMA (__builtin_elementwise_fma on
// ext_vector_type(2)) so the backend selects v_pk_fma_f32: 48 -> 24 FMA
// insts/step, per-wave issue 6.7 -> ~3.4 us. Same serial k-order per scalar
// chain -> bit-identical, absmax 0.0. Predicted kernel ~16.6 us, dur ~233.

#define BATCH 256
#define SEQ   336
#define DIMS  512
#define ORDER 24
#define TSEQ  168

typedef float f32x2 __attribute__((ext_vector_type(2)));

__global__ __launch_bounds__(256) void ar_rollout_kernel(
    const float* __restrict__ x,     // [BATCH, SEQ, DIMS]
    const float* __restrict__ W,     // [ORDER, 1]
    const float* __restrict__ bias,  // [1]
    float* __restrict__ out)         // [BATCH, TSEQ, DIMS]
{
    // One thread per (b, d-pair): d = 2*p, covers {d, d+1}.
    const int tid = blockIdx.x * blockDim.x + threadIdx.x;  // b*(DIMS/2) + p
    const int p = tid & (DIMS / 2 - 1);
    const int b = tid >> 8;          // tid / (DIMS/2)
    if (b >= BATCH) return;
    const int d = p * 2;

    // AR coefficients (wave-uniform -> scalar broadcasts) and bias.
    float wc[ORDER];
#pragma unroll
    for (int k = 0; k < ORDER; ++k) wc[k] = W[k];
    const float bb = bias[0];

    // Init window: x[b, SEQ-ORDER+k, {d,d+1}], k = 0..23 (oldest first).
    // Consecutive lanes = consecutive float2 -> each load is a coalesced
    // 512 B/wave dwordx2 burst.
    const f32x2* xp = (const f32x2*)(x + ((size_t)b * SEQ + (SEQ - ORDER)) * DIMS + d);
    f32x2 w[ORDER];
#pragma unroll
    for (int k = 0; k < ORDER; ++k) w[k] = xp[(size_t)k * (DIMS / 2)];

    // Rollout. At step j within a group, logical window element k lives in
    // physical register w[(j+k) % ORDER]; the new value overwrites w[j].
    // The two scalar chains advance in lockstep as ONE packed FMA per k
    // (v_pk_fma_f32): per-lane fused FMA, same serial k-order as R0 ->
    // bit-identical results (absmax 0.0) at half the instruction count.
    f32x2* op = (f32x2*)(out + (size_t)b * TSEQ * DIMS + d);
#pragma unroll 1
    for (int g = 0; g < TSEQ / ORDER; ++g) {
#pragma unroll
        for (int j = 0; j < ORDER; ++j) {
            f32x2 y2 = bb;            // splat: both chains start at bias
#pragma unroll
            for (int k = 0; k < ORDER; ++k) {
                const f32x2 wk = w[(j + k) % ORDER];
                const f32x2 ck = wc[k];   // splat of wave-uniform coeff
                y2 = __builtin_elementwise_fma(wk, ck, y2);
            }
            w[j] = y2;
            __builtin_nontemporal_store(y2, op);  // 88 MB stream, never re-read
            op += DIMS / 2;
        }
    }
}

extern "C" void kernel_launch(void* const* d_in, const int* in_sizes, int n_in,
                              void* d_out, int out_size, void* d_ws, size_t ws_size,
                              hipStream_t stream) {
    const float* x    = (const float*)d_in[0];
    const float* W    = (const float*)d_in[1];
    const float* bias = (const float*)d_in[2];
    // d_in[3] is tar_seq_len (==168), compile-time constant here.
    float* out = (float*)d_out;

    const int threads = 256;
    const int blocks  = (BATCH * DIMS / 2) / threads;  // 256 blocks, 1/CU
    ar_rollout_kernel<<<blocks, threads, 0, stream>>>(x, W, bias, out);
}